// Round 1
// baseline (342.336 us; speedup 1.0000x reference)
//
#include <hip/hip_runtime.h>
#include <hip/hip_bf16.h>

#define B_ 4
#define T_ 2048
#define C_ 1024
#define H_ 16
#define D_ 64
#define C3 3072

typedef __bf16 bf16x8 __attribute__((ext_vector_type(8)));
typedef __bf16 bf16x4 __attribute__((ext_vector_type(4)));
typedef float f32x4 __attribute__((ext_vector_type(4)));

__device__ __forceinline__ void gload_lds16(const void* g, void* lds) {
  __builtin_amdgcn_global_load_lds((const __attribute__((address_space(1))) void*)g,
                                   (__attribute__((address_space(3))) void*)lds, 16, 0, 0);
}

// byte offset into a tile with 128-byte rows (64 bf16), XOR-swizzled 16B chunks
__device__ __forceinline__ int swz128(int row, int chunk) {
  return row * 128 + ((chunk ^ (row & 7)) << 4);
}

// ---------------- cast x: fp32 -> bf16, vectorized ----------------
__global__ void cast_x_kernel(const float* __restrict__ in, __bf16* __restrict__ out, int n4) {
  int i = blockIdx.x * blockDim.x + threadIdx.x;
  if (i >= n4) return;
  float4 v = ((const float4*)in)[i];
  bf16x4 o;
  o.x = (__bf16)v.x; o.y = (__bf16)v.y; o.z = (__bf16)v.z; o.w = (__bf16)v.w;
  ((bf16x4*)out)[i] = o;
}

// ---------------- transpose + cast: fp32 [K][N] -> bf16 [N][K] ----------------
__global__ void transpose_cast_kernel(const float* __restrict__ in, __bf16* __restrict__ out,
                                      int K, int N) {
  __shared__ float tile[32][33];
  int kb = blockIdx.y * 32, nb = blockIdx.x * 32;
  int tx = threadIdx.x, ty = threadIdx.y;
#pragma unroll
  for (int i = 0; i < 4; i++) {
    int r = ty + i * 8;
    tile[r][tx] = in[(size_t)(kb + r) * N + nb + tx];
  }
  __syncthreads();
#pragma unroll
  for (int i = 0; i < 4; i++) {
    int r = ty + i * 8;
    out[(size_t)(nb + r) * K + kb + tx] = (__bf16)tile[tx][r];
  }
}

// ---------------- GEMM: C[M,N] = A[M,K] * Bt[N,K]^T  (bf16 in, f32 acc) ----------------
template <bool OUTF32>
__global__ __launch_bounds__(256) void gemm_bt_kernel(const __bf16* __restrict__ A,
                                                      const __bf16* __restrict__ Bt,
                                                      __bf16* __restrict__ Cb,
                                                      float* __restrict__ Cf,
                                                      int M, int N, int K) {
  __shared__ char ldsbuf[2 * 128 * 128];  // A tile 16KB + B tile 16KB (BK=64 bf16)
  char* ldsA = ldsbuf;
  char* ldsB = ldsbuf + 128 * 128;
  int tid = threadIdx.x, w = tid >> 6, l = tid & 63;
  int m0 = blockIdx.y * 128, n0 = blockIdx.x * 128;
  int wr = w >> 1, wc = w & 1;
  int lr = l & 15, lhi = l >> 4;
  f32x4 acc[4][4];
#pragma unroll
  for (int m = 0; m < 4; m++)
#pragma unroll
    for (int n = 0; n < 4; n++) acc[m][n] = (f32x4){0.f, 0.f, 0.f, 0.f};

  int nK = K >> 6;
  for (int kt = 0; kt < nK; kt++) {
    int k0 = kt << 6;
    __syncthreads();
#pragma unroll
    for (int jj = 0; jj < 4; jj++) {
      int q = w * 4 + jj;
      int row = q * 8 + (l >> 3);
      int cg = (l & 7) ^ ((l >> 3) & 7);  // pre-swizzled global source chunk
      gload_lds16(A + (size_t)(m0 + row) * K + k0 + cg * 8, ldsA + q * 1024);
      gload_lds16(Bt + (size_t)(n0 + row) * K + k0 + cg * 8, ldsB + q * 1024);
    }
    __syncthreads();
    bf16x8 af[4][2], bfr[4][2];
#pragma unroll
    for (int m = 0; m < 4; m++) {
      int r = wr * 64 + m * 16 + lr;
#pragma unroll
      for (int kc = 0; kc < 2; kc++)
        af[m][kc] = *(const bf16x8*)(ldsA + swz128(r, kc * 4 + lhi));
    }
#pragma unroll
    for (int n = 0; n < 4; n++) {
      int r = wc * 64 + n * 16 + lr;
#pragma unroll
      for (int kc = 0; kc < 2; kc++)
        bfr[n][kc] = *(const bf16x8*)(ldsB + swz128(r, kc * 4 + lhi));
    }
#pragma unroll
    for (int kc = 0; kc < 2; kc++)
#pragma unroll
      for (int m = 0; m < 4; m++)
#pragma unroll
        for (int n = 0; n < 4; n++)
          acc[m][n] =
              __builtin_amdgcn_mfma_f32_16x16x32_bf16(af[m][kc], bfr[n][kc], acc[m][n], 0, 0, 0);
  }

#pragma unroll
  for (int m = 0; m < 4; m++)
#pragma unroll
    for (int n = 0; n < 4; n++)
#pragma unroll
      for (int i = 0; i < 4; i++) {
        int rg = m0 + wr * 64 + m * 16 + lhi * 4 + i;
        int cg = n0 + wc * 64 + n * 16 + lr;
        if (OUTF32)
          Cf[(size_t)rg * N + cg] = acc[m][n][i];
        else
          Cb[(size_t)rg * N + cg] = (__bf16)acc[m][n][i];
      }
}

// ---------------- causal flash attention ----------------
// grid: (T/64, B*H); block 256 = 4 waves, wave w owns 16 q-rows
__global__ __launch_bounds__(256) void attn_kernel(const __bf16* __restrict__ qkv,
                                                   __bf16* __restrict__ y) {
  __shared__ char ldsK[64 * 128];      // K tile [kv][d], swizzled
  __shared__ char ldsV[64 * 128];      // V^T tile [d][kv], swizzled
  __shared__ char ldsP[4][16 * 128];   // per-wave P tile [q][kv], swizzled
  int tid = threadIdx.x, w = tid >> 6, l = tid & 63;
  int qb = blockIdx.x, bh = blockIdx.y, b = bh >> 4, h = bh & 15;
  size_t base = (size_t)b * T_ * C3;
  int q0w = qb * 64 + w * 16;
  int lr = l & 15, lhi = l >> 4;

  // Q fragments in registers (A-operand layout: row = lane%16, k = (lane/16)*8+j)
  bf16x8 qf[2];
  {
    const __bf16* qp = qkv + base + (size_t)(q0w + lr) * C3 + h * D_;
    qf[0] = *(const bf16x8*)(qp + lhi * 8);
    qf[1] = *(const bf16x8*)(qp + 32 + lhi * 8);
  }

  f32x4 o[4];
#pragma unroll
  for (int nf = 0; nf < 4; nf++) o[nf] = (f32x4){0.f, 0.f, 0.f, 0.f};
  float mrun[4], lrun[4];
#pragma unroll
  for (int i = 0; i < 4; i++) { mrun[i] = -__builtin_inff(); lrun[i] = 0.f; }

  for (int kt = 0; kt <= qb; kt++) {
    __syncthreads();
    // stage K via global_load_lds, pre-swizzled source
#pragma unroll
    for (int jj = 0; jj < 2; jj++) {
      int j = w * 2 + jj;
      int row = j * 8 + (l >> 3);
      int cg = (l & 7) ^ ((l >> 3) & 7);
      gload_lds16(qkv + base + (size_t)(kt * 64 + row) * C3 + C_ + h * D_ + cg * 8,
                  ldsK + j * 1024);
    }
    // stage V transposed ([d][kv]) via registers, swizzled scalar writes
#pragma unroll
    for (int it = 0; it < 2; it++) {
      int kv = tid & 63;
      int dc = (tid >> 6) + it * 4;
      union { int4 v; __bf16 hh[8]; } u;
      u.v = *(const int4*)(qkv + base + (size_t)(kt * 64 + kv) * C3 + 2 * C_ + h * D_ + dc * 8);
#pragma unroll
      for (int e = 0; e < 8; e++) {
        int d = dc * 8 + e;
        *(__bf16*)(ldsV + d * 128 + (((kv >> 3) ^ (d & 7)) << 4) + (kv & 7) * 2) = u.hh[e];
      }
    }
    __syncthreads();

    // S = Q K^T
    f32x4 s[4];
#pragma unroll
    for (int nf = 0; nf < 4; nf++) {
      s[nf] = (f32x4){0.f, 0.f, 0.f, 0.f};
#pragma unroll
      for (int kc = 0; kc < 2; kc++) {
        bf16x8 kf = *(const bf16x8*)(ldsK + swz128(nf * 16 + lr, kc * 4 + lhi));
        s[nf] = __builtin_amdgcn_mfma_f32_16x16x32_bf16(qf[kc], kf, s[nf], 0, 0, 0);
      }
    }

    // scale + causal mask (diagonal tile only)
    bool diag = (kt == qb);
#pragma unroll
    for (int nf = 0; nf < 4; nf++)
#pragma unroll
      for (int i = 0; i < 4; i++) {
        float v = s[nf][i] * 0.125f;
        if (diag && (kt * 64 + nf * 16 + lr) > (q0w + lhi * 4 + i)) v = -1e30f;
        s[nf][i] = v;
      }

    // online softmax: row max over 16 lanes
    float tmax[4];
#pragma unroll
    for (int i = 0; i < 4; i++)
      tmax[i] = fmaxf(fmaxf(s[0][i], s[1][i]), fmaxf(s[2][i], s[3][i]));
#pragma unroll
    for (int dd = 1; dd < 16; dd <<= 1)
#pragma unroll
      for (int i = 0; i < 4; i++) tmax[i] = fmaxf(tmax[i], __shfl_xor(tmax[i], dd));

    float alpha[4], rsum[4];
#pragma unroll
    for (int i = 0; i < 4; i++) {
      float mn = fmaxf(mrun[i], tmax[i]);
      alpha[i] = __expf(mrun[i] - mn);
      mrun[i] = mn;
    }
#pragma unroll
    for (int nf = 0; nf < 4; nf++)
#pragma unroll
      for (int i = 0; i < 4; i++) s[nf][i] = __expf(s[nf][i] - mrun[i]);
#pragma unroll
    for (int i = 0; i < 4; i++) rsum[i] = (s[0][i] + s[1][i]) + (s[2][i] + s[3][i]);
#pragma unroll
    for (int dd = 1; dd < 16; dd <<= 1)
#pragma unroll
      for (int i = 0; i < 4; i++) rsum[i] += __shfl_xor(rsum[i], dd);
#pragma unroll
    for (int i = 0; i < 4; i++) lrun[i] = lrun[i] * alpha[i] + rsum[i];
#pragma unroll
    for (int nf = 0; nf < 4; nf++)
#pragma unroll
      for (int i = 0; i < 4; i++) o[nf][i] *= alpha[i];

    // P (D-layout) -> per-wave LDS (swizzled) -> A-layout fragments
    char* pb = &ldsP[w][0];
#pragma unroll
    for (int nf = 0; nf < 4; nf++)
#pragma unroll
      for (int i = 0; i < 4; i++) {
        int row = lhi * 4 + i, col = nf * 16 + lr;
        *(__bf16*)(pb + row * 128 + (((col >> 3) ^ (row & 7)) << 4) + (col & 7) * 2) =
            (__bf16)s[nf][i];
      }

    bf16x8 pa[2];
#pragma unroll
    for (int kc = 0; kc < 2; kc++)
      pa[kc] = *(const bf16x8*)(pb + swz128(lr, kc * 4 + lhi));
#pragma unroll
    for (int nf = 0; nf < 4; nf++)
#pragma unroll
      for (int kc = 0; kc < 2; kc++) {
        bf16x8 vf = *(const bf16x8*)(ldsV + swz128(nf * 16 + lr, kc * 4 + lhi));
        o[nf] = __builtin_amdgcn_mfma_f32_16x16x32_bf16(pa[kc], vf, o[nf], 0, 0, 0);
      }
  }

  // epilogue: y[b,t,h*64+d] = O / l
#pragma unroll
  for (int nf = 0; nf < 4; nf++)
#pragma unroll
    for (int i = 0; i < 4; i++) {
      int rg = q0w + lhi * 4 + i;
      int cg = h * D_ + nf * 16 + lr;
      y[(size_t)(b * T_ + rg) * C_ + cg] = (__bf16)(o[nf][i] / lrun[i]);
    }
}

extern "C" void kernel_launch(void* const* d_in, const int* in_sizes, int n_in,
                              void* d_out, int out_size, void* d_ws, size_t ws_size,
                              hipStream_t stream) {
  const float* x = (const float*)d_in[0];
  const float* Wa = (const float*)d_in[1];
  const float* Wp = (const float*)d_in[2];
  float* out = (float*)d_out;
  char* ws = (char*)d_ws;

  // workspace layout (bytes)
  __bf16* xb  = (__bf16*)(ws);                       // 8192*1024*2  = 16777216
  __bf16* wat = (__bf16*)(ws + 16777216);            // 3072*1024*2  = 6291456
  __bf16* wpt = (__bf16*)(ws + 23068672);            // 1024*1024*2  = 2097152
  __bf16* qkv = (__bf16*)(ws + 25165824);            // 8192*3072*2  = 50331648
  __bf16* yb  = (__bf16*)(ws + 75497472);            // 8192*1024*2  = 16777216

  cast_x_kernel<<<8192, 256, 0, stream>>>(x, xb, (B_ * T_ * C_) / 4);
  transpose_cast_kernel<<<dim3(C3 / 32, C_ / 32), dim3(32, 8), 0, stream>>>(Wa, wat, C_, C3);
  transpose_cast_kernel<<<dim3(C_ / 32, C_ / 32), dim3(32, 8), 0, stream>>>(Wp, wpt, C_, C_);

  // qkv = x @ W_attn   [8192,1024]x[1024,3072]
  gemm_bt_kernel<false><<<dim3(C3 / 128, (B_ * T_) / 128), 256, 0, stream>>>(
      xb, wat, qkv, nullptr, B_ * T_, C3, C_);

  // attention
  attn_kernel<<<dim3(T_ / 64, B_ * H_), 256, 0, stream>>>(qkv, yb);

  // out = y @ W_proj   [8192,1024]x[1024,1024], f32 out
  gemm_bt_kernel<true><<<dim3(C_ / 128, (B_ * T_) / 128), 256, 0, stream>>>(
      yb, wpt, nullptr, out, B_ * T_, C_, C_);
}

// Round 2
// 202.306 us; speedup vs baseline: 1.6922x; 1.6922x over previous
//
#include <hip/hip_runtime.h>
#include <hip/hip_bf16.h>

#define B_ 4
#define T_ 2048
#define C_ 1024
#define H_ 16
#define D_ 64
#define C3 3072

typedef __bf16 bf16x8 __attribute__((ext_vector_type(8)));
typedef __bf16 bf16x4 __attribute__((ext_vector_type(4)));
typedef float f32x4 __attribute__((ext_vector_type(4)));
typedef float f32x16 __attribute__((ext_vector_type(16)));
typedef unsigned u32x4 __attribute__((ext_vector_type(4)));

__device__ __forceinline__ void gload_lds16(const void* g, void* lds) {
  __builtin_amdgcn_global_load_lds((const __attribute__((address_space(1))) void*)g,
                                   (__attribute__((address_space(3))) void*)lds, 16, 0, 0);
}

// byte offset into a tile with 128-byte rows (64 bf16), XOR-swizzled 16B chunks
__device__ __forceinline__ int swz128(int row, int chunk) {
  return row * 128 + ((chunk ^ (row & 7)) << 4);
}

__device__ __forceinline__ unsigned cvt_pk_bf16(float a, float b) {
  unsigned r;
  asm("v_cvt_pk_bf16_f32 %0, %1, %2" : "=v"(r) : "v"(a), "v"(b));
  return r;
}

__device__ __forceinline__ void pl32swap(unsigned& x, unsigned& y) {
  asm volatile("v_permlane32_swap_b32 %0, %1" : "+v"(x), "+v"(y));
}

// ---------------- cast x: fp32 -> bf16, vectorized ----------------
__global__ void cast_x_kernel(const float* __restrict__ in, __bf16* __restrict__ out, int n4) {
  int i = blockIdx.x * blockDim.x + threadIdx.x;
  if (i >= n4) return;
  float4 v = ((const float4*)in)[i];
  bf16x4 o;
  o.x = (__bf16)v.x; o.y = (__bf16)v.y; o.z = (__bf16)v.z; o.w = (__bf16)v.w;
  ((bf16x4*)out)[i] = o;
}

// ---------------- transpose + cast: fp32 [K][N] -> bf16 [N][K] ----------------
__global__ void transpose_cast_kernel(const float* __restrict__ in, __bf16* __restrict__ out,
                                      int K, int N) {
  __shared__ float tile[32][33];
  int kb = blockIdx.y * 32, nb = blockIdx.x * 32;
  int tx = threadIdx.x, ty = threadIdx.y;
#pragma unroll
  for (int i = 0; i < 4; i++) {
    int r = ty + i * 8;
    tile[r][tx] = in[(size_t)(kb + r) * N + nb + tx];
  }
  __syncthreads();
#pragma unroll
  for (int i = 0; i < 4; i++) {
    int r = ty + i * 8;
    out[(size_t)(nb + r) * K + kb + tx] = (__bf16)tile[tx][r];
  }
}

// ---------------- GEMM: C[M,N] = A[M,K] * Bt[N,K]^T  (bf16 in, f32 acc) ----------------
template <bool OUTF32>
__global__ __launch_bounds__(256) void gemm_bt_kernel(const __bf16* __restrict__ A,
                                                      const __bf16* __restrict__ Bt,
                                                      __bf16* __restrict__ Cb,
                                                      float* __restrict__ Cf,
                                                      int M, int N, int K) {
  __shared__ char ldsbuf[2 * 128 * 128];
  char* ldsA = ldsbuf;
  char* ldsB = ldsbuf + 128 * 128;
  int tid = threadIdx.x, w = tid >> 6, l = tid & 63;
  int m0 = blockIdx.y * 128, n0 = blockIdx.x * 128;
  int wr = w >> 1, wc = w & 1;
  int lr = l & 15, lhi = l >> 4;
  f32x4 acc[4][4];
#pragma unroll
  for (int m = 0; m < 4; m++)
#pragma unroll
    for (int n = 0; n < 4; n++) acc[m][n] = (f32x4){0.f, 0.f, 0.f, 0.f};

  int nK = K >> 6;
  for (int kt = 0; kt < nK; kt++) {
    int k0 = kt << 6;
    __syncthreads();
#pragma unroll
    for (int jj = 0; jj < 4; jj++) {
      int q = w * 4 + jj;
      int row = q * 8 + (l >> 3);
      int cg = (l & 7) ^ ((l >> 3) & 7);
      gload_lds16(A + (size_t)(m0 + row) * K + k0 + cg * 8, ldsA + q * 1024);
      gload_lds16(Bt + (size_t)(n0 + row) * K + k0 + cg * 8, ldsB + q * 1024);
    }
    __syncthreads();
    bf16x8 af[4][2], bfr[4][2];
#pragma unroll
    for (int m = 0; m < 4; m++) {
      int r = wr * 64 + m * 16 + lr;
#pragma unroll
      for (int kc = 0; kc < 2; kc++)
        af[m][kc] = *(const bf16x8*)(ldsA + swz128(r, kc * 4 + lhi));
    }
#pragma unroll
    for (int n = 0; n < 4; n++) {
      int r = wc * 64 + n * 16 + lr;
#pragma unroll
      for (int kc = 0; kc < 2; kc++)
        bfr[n][kc] = *(const bf16x8*)(ldsB + swz128(r, kc * 4 + lhi));
    }
#pragma unroll
    for (int kc = 0; kc < 2; kc++)
#pragma unroll
      for (int m = 0; m < 4; m++)
#pragma unroll
        for (int n = 0; n < 4; n++)
          acc[m][n] =
              __builtin_amdgcn_mfma_f32_16x16x32_bf16(af[m][kc], bfr[n][kc], acc[m][n], 0, 0, 0);
  }

#pragma unroll
  for (int m = 0; m < 4; m++)
#pragma unroll
    for (int n = 0; n < 4; n++)
#pragma unroll
      for (int i = 0; i < 4; i++) {
        int rg = m0 + wr * 64 + m * 16 + lhi * 4 + i;
        int cg = n0 + wc * 64 + n * 16 + lr;
        if (OUTF32)
          Cf[(size_t)rg * N + cg] = acc[m][n][i];
        else
          Cb[(size_t)rg * N + cg] = (__bf16)acc[m][n][i];
      }
}

// ---------------- causal flash attention, swapped-QK^T 32x32 ----------------
// 1024 blocks (XCD-chunk swizzled), 4 waves; wave owns 32 q rows, lane owns 1 q row.
__global__ __launch_bounds__(256) void attn_kernel(const __bf16* __restrict__ qkv,
                                                   __bf16* __restrict__ y) {
  __shared__ __align__(16) char ldsK[64 * 128];  // K tile [kv][d], swizzled
  __shared__ __align__(16) char ldsV[64 * 128];  // V^T tile [d][kv], swizzled
  int tid = threadIdx.x, w = tid >> 6, l = tid & 63;
  int bid = blockIdx.x;
  int lin = (bid & 7) * 128 + (bid >> 3);  // XCD-chunked: 8 heads' K/V per XCD L2
  int qb = lin & 15, bh = lin >> 4, b = bh >> 4, h = bh & 15;
  size_t base = (size_t)b * T_ * C3;
  int lq = l & 31, hi = l >> 5;
  int qrow = qb * 128 + w * 32 + lq;

  // Q as B-operand fragments: qf[c] = Q[qrow][c*16 + hi*8 + j]
  bf16x8 qf[4];
  {
    const __bf16* qp = qkv + base + (size_t)qrow * C3 + h * D_;
#pragma unroll
    for (int c = 0; c < 4; c++) qf[c] = *(const bf16x8*)(qp + c * 16 + hi * 8);
  }

  f32x16 o[2];
#pragma unroll
  for (int d = 0; d < 2; d++)
#pragma unroll
    for (int i = 0; i < 16; i++) o[d][i] = 0.f;
  float mrun = -__builtin_inff(), lrun = 0.f;

  int nt = 2 * qb + 2;
  const __bf16* vbase = qkv + base + 2 * C_ + h * D_;
  int kvl = tid & 63, dc0 = tid >> 6;

  // prefetch V tile 0 into regs (T14: issue early, write after barrier)
  int4 vpre[2];
#pragma unroll
  for (int it = 0; it < 2; it++)
    vpre[it] = *(const int4*)(vbase + (size_t)kvl * C3 + (dc0 + it * 4) * 8);

  for (int kt = 0; kt < nt; kt++) {
    __syncthreads();  // all waves done with previous tile's LDS
    // stage K via global_load_lds, pre-swizzled source
#pragma unroll
    for (int jj = 0; jj < 2; jj++) {
      int j = w * 2 + jj;
      int row = j * 8 + (l >> 3);
      int cg = (l & 7) ^ ((l >> 3) & 7);
      gload_lds16(qkv + base + (size_t)(kt * 64 + row) * C3 + C_ + h * D_ + cg * 8,
                  ldsK + j * 1024);
    }
    // write V^T (swizzled) from prefetched regs
#pragma unroll
    for (int it = 0; it < 2; it++) {
      int dc = dc0 + it * 4;
      union { int4 v; __bf16 hh[8]; } u;
      u.v = vpre[it];
#pragma unroll
      for (int e = 0; e < 8; e++) {
        int d = dc * 8 + e;
        *(__bf16*)(ldsV + d * 128 + (((kvl >> 3) ^ (d & 7)) << 4) + (kvl & 7) * 2) = u.hh[e];
      }
    }
    __syncthreads();
    // prefetch next V tile (overlaps with compute below)
    if (kt + 1 < nt) {
#pragma unroll
      for (int it = 0; it < 2; it++)
        vpre[it] =
            *(const int4*)(vbase + (size_t)((kt + 1) * 64 + kvl) * C3 + (dc0 + it * 4) * 8);
    }

    // waves whose q-rows are entirely below this kv tile skip compute (uniform branch)
    if (kt * 64 > qb * 128 + w * 32 + 31) continue;

    // S^T[kv][q] = K · Q^T : lane holds 32 kv values of its q row
    f32x16 s[2];
#pragma unroll
    for (int b2 = 0; b2 < 2; b2++) {
#pragma unroll
      for (int i = 0; i < 16; i++) s[b2][i] = 0.f;
#pragma unroll
      for (int c = 0; c < 4; c++) {
        bf16x8 kf = *(const bf16x8*)(ldsK + swz128(b2 * 32 + lq, 2 * c + hi));
        s[b2] = __builtin_amdgcn_mfma_f32_32x32x16_bf16(kf, qf[c], s[b2], 0, 0, 0);
      }
    }

    // scale + causal mask
    bool needmask = (kt * 64 + 63) > (qb * 128 + w * 32);
#pragma unroll
    for (int b2 = 0; b2 < 2; b2++)
#pragma unroll
      for (int r = 0; r < 16; r++) {
        float v = s[b2][r] * 0.125f;
        if (needmask) {
          int kv = kt * 64 + b2 * 32 + (r & 3) + 8 * (r >> 2) + 4 * hi;
          if (kv > qrow) v = -1e30f;
        }
        s[b2][r] = v;
      }

    // row max: in-lane tree + one cross-half swap
    float vm[16];
#pragma unroll
    for (int r = 0; r < 16; r++) vm[r] = fmaxf(s[0][r], s[1][r]);
#pragma unroll
    for (int st = 8; st >= 1; st >>= 1)
#pragma unroll
      for (int r = 0; r < st; r++) vm[r] = fmaxf(vm[r], vm[r + st]);
    float tmax = fmaxf(vm[0], __shfl_xor(vm[0], 32));
    float mnew = fmaxf(mrun, tmax);
    float alpha = __expf(mrun - mnew);
    mrun = mnew;

    // p = exp(s - m)
#pragma unroll
    for (int b2 = 0; b2 < 2; b2++)
#pragma unroll
      for (int r = 0; r < 16; r++) s[b2][r] = __expf(s[b2][r] - mnew);

    // row sum
    float vs[16];
#pragma unroll
    for (int r = 0; r < 16; r++) vs[r] = s[0][r] + s[1][r];
#pragma unroll
    for (int st = 8; st >= 1; st >>= 1)
#pragma unroll
      for (int r = 0; r < st; r++) vs[r] += vs[r + st];
    float rsum = vs[0] + __shfl_xor(vs[0], 32);
    lrun = lrun * alpha + rsum;
#pragma unroll
    for (int d = 0; d < 2; d++)
#pragma unroll
      for (int i = 0; i < 16; i++) o[d][i] *= alpha;

    // P^T -> B-operand fragments via cvt_pk + permlane32_swap (no LDS)
    bf16x8 pa[4];
#pragma unroll
    for (int b2 = 0; b2 < 2; b2++) {
      unsigned wg[4][2];
#pragma unroll
      for (int g = 0; g < 4; g++) {
        wg[g][0] = cvt_pk_bf16(s[b2][4 * g + 0], s[b2][4 * g + 1]);
        wg[g][1] = cvt_pk_bf16(s[b2][4 * g + 2], s[b2][4 * g + 3]);
      }
#pragma unroll
      for (int cp = 0; cp < 2; cp++) {
        unsigned x0 = wg[2 * cp][0], x1 = wg[2 * cp][1];
        unsigned y0 = wg[2 * cp + 1][0], y1 = wg[2 * cp + 1][1];
        pl32swap(x0, y0);
        pl32swap(x1, y1);
        union { u32x4 u; bf16x8 h; } uu;
        uu.u = (u32x4){x0, x1, y0, y1};
        pa[b2 * 2 + cp] = uu.h;
      }
    }

    // O^T[d][q] += V^T · P^T
#pragma unroll
    for (int db = 0; db < 2; db++)
#pragma unroll
      for (int c = 0; c < 4; c++) {
        bf16x8 vf = *(const bf16x8*)(ldsV + swz128(db * 32 + lq, 2 * c + hi));
        o[db] = __builtin_amdgcn_mfma_f32_32x32x16_bf16(vf, pa[c], o[db], 0, 0, 0);
      }
  }

  // epilogue: lane owns q-row qrow; d = db*32 + 8*rr + 4*hi + i
  float inv = 1.f / lrun;
  __bf16* yp = y + (size_t)(b * T_ + qrow) * C_ + h * D_;
#pragma unroll
  for (int db = 0; db < 2; db++)
#pragma unroll
    for (int rr = 0; rr < 4; rr++) {
      bf16x4 ov;
#pragma unroll
      for (int i = 0; i < 4; i++) ov[i] = (__bf16)(o[db][rr * 4 + i] * inv);
      *(bf16x4*)(yp + db * 32 + rr * 8 + hi * 4) = ov;
    }
}

extern "C" void kernel_launch(void* const* d_in, const int* in_sizes, int n_in,
                              void* d_out, int out_size, void* d_ws, size_t ws_size,
                              hipStream_t stream) {
  const float* x = (const float*)d_in[0];
  const float* Wa = (const float*)d_in[1];
  const float* Wp = (const float*)d_in[2];
  float* out = (float*)d_out;
  char* ws = (char*)d_ws;

  __bf16* xb  = (__bf16*)(ws);
  __bf16* wat = (__bf16*)(ws + 16777216);
  __bf16* wpt = (__bf16*)(ws + 23068672);
  __bf16* qkv = (__bf16*)(ws + 25165824);
  __bf16* yb  = (__bf16*)(ws + 75497472);

  cast_x_kernel<<<8192, 256, 0, stream>>>(x, xb, (B_ * T_ * C_) / 4);
  transpose_cast_kernel<<<dim3(C3 / 32, C_ / 32), dim3(32, 8), 0, stream>>>(Wa, wat, C_, C3);
  transpose_cast_kernel<<<dim3(C_ / 32, C_ / 32), dim3(32, 8), 0, stream>>>(Wp, wpt, C_, C_);

  gemm_bt_kernel<false><<<dim3(C3 / 128, (B_ * T_) / 128), 256, 0, stream>>>(
      xb, wat, qkv, nullptr, B_ * T_, C3, C_);

  attn_kernel<<<dim3(1024), 256, 0, stream>>>(qkv, yb);

  gemm_bt_kernel<true><<<dim3(C_ / 128, (B_ * T_) / 128), 256, 0, stream>>>(
      yb, wpt, nullptr, out, B_ * T_, C_, C_);
}

// Round 3
// 177.942 us; speedup vs baseline: 1.9239x; 1.1369x over previous
//
#include <hip/hip_runtime.h>
#include <hip/hip_bf16.h>

#define B_ 4
#define T_ 2048
#define C_ 1024
#define H_ 16
#define D_ 64
#define C3 3072

typedef __bf16 bf16x8 __attribute__((ext_vector_type(8)));
typedef __bf16 bf16x4 __attribute__((ext_vector_type(4)));
typedef float f32x4 __attribute__((ext_vector_type(4)));
typedef float f32x16 __attribute__((ext_vector_type(16)));
typedef unsigned u32x4 __attribute__((ext_vector_type(4)));

// 0.125 (1/sqrt(D)) * log2(e): softmax computed in exp2 domain
#define SCALE_LOG2E 0.1803368801111244f

__device__ __forceinline__ void gload_lds16(const void* g, void* lds) {
  __builtin_amdgcn_global_load_lds((const __attribute__((address_space(1))) void*)g,
                                   (__attribute__((address_space(3))) void*)lds, 16, 0, 0);
}

// byte offset into a tile with 128-byte rows (64 bf16), XOR-swizzled 16B chunks
__device__ __forceinline__ int swz128(int row, int chunk) {
  return row * 128 + ((chunk ^ (row & 7)) << 4);
}

__device__ __forceinline__ unsigned cvt_pk_bf16(float a, float b) {
  unsigned r;
  asm("v_cvt_pk_bf16_f32 %0, %1, %2" : "=v"(r) : "v"(a), "v"(b));
  return r;
}

__device__ __forceinline__ void pl32swap(unsigned& x, unsigned& y) {
  asm volatile("v_permlane32_swap_b32 %0, %1" : "+v"(x), "+v"(y));
}

// ---------------- cast x: fp32 -> bf16, vectorized ----------------
__global__ void cast_x_kernel(const float* __restrict__ in, __bf16* __restrict__ out, int n4) {
  int i = blockIdx.x * blockDim.x + threadIdx.x;
  if (i >= n4) return;
  float4 v = ((const float4*)in)[i];
  bf16x4 o;
  o.x = (__bf16)v.x; o.y = (__bf16)v.y; o.z = (__bf16)v.z; o.w = (__bf16)v.w;
  ((bf16x4*)out)[i] = o;
}

// ---------------- transpose + cast: fp32 [K][N] -> bf16 [N][K] ----------------
__global__ void transpose_cast_kernel(const float* __restrict__ in, __bf16* __restrict__ out,
                                      int K, int N) {
  __shared__ float tile[32][33];
  int kb = blockIdx.y * 32, nb = blockIdx.x * 32;
  int tx = threadIdx.x, ty = threadIdx.y;
#pragma unroll
  for (int i = 0; i < 4; i++) {
    int r = ty + i * 8;
    tile[r][tx] = in[(size_t)(kb + r) * N + nb + tx];
  }
  __syncthreads();
#pragma unroll
  for (int i = 0; i < 4; i++) {
    int r = ty + i * 8;
    out[(size_t)(nb + r) * K + kb + tx] = (__bf16)tile[tx][r];
  }
}

// ---------------- transpose V out of qkv: [b][t][2C+hv] -> vT[b*1024+hv][t] ----------------
__global__ void transpose_v_kernel(const __bf16* __restrict__ qkv, __bf16* __restrict__ vT) {
  __shared__ __bf16 tile[32][33];
  int b = blockIdx.z;
  int t0 = blockIdx.x * 32, hv0 = blockIdx.y * 32;
  int tx = threadIdx.x, ty = threadIdx.y;
  const __bf16* src = qkv + (size_t)b * T_ * C3 + 2 * C_;
#pragma unroll
  for (int i = 0; i < 4; i++) {
    int r = ty + i * 8;
    tile[r][tx] = src[(size_t)(t0 + r) * C3 + hv0 + tx];
  }
  __syncthreads();
#pragma unroll
  for (int i = 0; i < 4; i++) {
    int r = ty + i * 8;
    vT[((size_t)b * 1024 + hv0 + r) * T_ + t0 + tx] = tile[tx][r];
  }
}

// ---------------- GEMM: C[M,N] = A[M,K] * Bt[N,K]^T  (bf16 in, f32 acc) ----------------
template <bool OUTF32>
__global__ __launch_bounds__(256) void gemm_bt_kernel(const __bf16* __restrict__ A,
                                                      const __bf16* __restrict__ Bt,
                                                      __bf16* __restrict__ Cb,
                                                      float* __restrict__ Cf,
                                                      int M, int N, int K) {
  __shared__ char ldsbuf[2 * 128 * 128];
  char* ldsA = ldsbuf;
  char* ldsB = ldsbuf + 128 * 128;
  int tid = threadIdx.x, w = tid >> 6, l = tid & 63;
  // XCD-chunked swizzle (nwg % 8 == 0 for both GEMMs)
  int gx = gridDim.x;
  int nwg = gx * gridDim.y;
  int orig = blockIdx.y * gx + blockIdx.x;
  int cpx = nwg >> 3;
  int swz = (orig & 7) * cpx + (orig >> 3);
  int bx = swz % gx, by = swz / gx;
  int m0 = by * 128, n0 = bx * 128;
  int wr = w >> 1, wc = w & 1;
  int lr = l & 15, lhi = l >> 4;
  f32x4 acc[4][4];
#pragma unroll
  for (int m = 0; m < 4; m++)
#pragma unroll
    for (int n = 0; n < 4; n++) acc[m][n] = (f32x4){0.f, 0.f, 0.f, 0.f};

  int nK = K >> 6;
  for (int kt = 0; kt < nK; kt++) {
    int k0 = kt << 6;
    __syncthreads();
#pragma unroll
    for (int jj = 0; jj < 4; jj++) {
      int q = w * 4 + jj;
      int row = q * 8 + (l >> 3);
      int cg = (l & 7) ^ ((l >> 3) & 7);
      gload_lds16(A + (size_t)(m0 + row) * K + k0 + cg * 8, ldsA + q * 1024);
      gload_lds16(Bt + (size_t)(n0 + row) * K + k0 + cg * 8, ldsB + q * 1024);
    }
    __syncthreads();
    bf16x8 af[4][2], bfr[4][2];
#pragma unroll
    for (int m = 0; m < 4; m++) {
      int r = wr * 64 + m * 16 + lr;
#pragma unroll
      for (int kc = 0; kc < 2; kc++)
        af[m][kc] = *(const bf16x8*)(ldsA + swz128(r, kc * 4 + lhi));
    }
#pragma unroll
    for (int n = 0; n < 4; n++) {
      int r = wc * 64 + n * 16 + lr;
#pragma unroll
      for (int kc = 0; kc < 2; kc++)
        bfr[n][kc] = *(const bf16x8*)(ldsB + swz128(r, kc * 4 + lhi));
    }
#pragma unroll
    for (int kc = 0; kc < 2; kc++)
#pragma unroll
      for (int m = 0; m < 4; m++)
#pragma unroll
        for (int n = 0; n < 4; n++)
          acc[m][n] =
              __builtin_amdgcn_mfma_f32_16x16x32_bf16(af[m][kc], bfr[n][kc], acc[m][n], 0, 0, 0);
  }

#pragma unroll
  for (int m = 0; m < 4; m++)
#pragma unroll
    for (int n = 0; n < 4; n++)
#pragma unroll
      for (int i = 0; i < 4; i++) {
        int rg = m0 + wr * 64 + m * 16 + lhi * 4 + i;
        int cg = n0 + wc * 64 + n * 16 + lr;
        if (OUTF32)
          Cf[(size_t)rg * N + cg] = acc[m][n][i];
        else
          Cb[(size_t)rg * N + cg] = (__bf16)acc[m][n][i];
      }
}

// ---------------- causal flash attention, swapped-QK^T 32x32, double-buffered ----------------
// 1024 blocks; wave owns 32 q rows, lane owns 1 q row (full P row in regs).
__global__ __launch_bounds__(256) void attn_kernel(const __bf16* __restrict__ qkv,
                                                   const __bf16* __restrict__ vT,
                                                   __bf16* __restrict__ y) {
  __shared__ __align__(16) char lds[2][16384];  // [buf][ K(8KB,[kv][d]) | V^T(8KB,[d][kv]) ]
  int tid = threadIdx.x, w = tid >> 6, l = tid & 63;

  // work-balance map: 4 co-resident blocks per CU (bids = mod-256 apart) sum to const work;
  // all qb of one bh share an XCD (bid&7 == bh&7) for K/V L2 reuse.
  int g = blockIdx.x >> 6, bh = blockIdx.x & 63;
  int q2 = g >> 2;
  int qb = (q2 & 1) ? ((q2 == 1) ? g + 4 : g - 12) : (15 - g);
  int b = bh >> 4, h = bh & 15;
  size_t base = (size_t)b * T_ * C3;
  int lq = l & 31, hi = l >> 5;
  int qrow = qb * 128 + w * 32 + lq;
  int q0w = qb * 128 + w * 32;

  // staging source pointers (pre-swizzled chunk)
  int lrow = l >> 3;
  int cg = (l & 7) ^ (lrow & 7);
  const __bf16* kptr = qkv + base + (size_t)(w * 16 + lrow) * C3 + C_ + h * D_ + cg * 8;
  const __bf16* vptr = vT + ((size_t)bh * D_ + w * 16 + lrow) * T_ + cg * 8;

  // Q as B-operand fragments
  bf16x8 qf[4];
  {
    const __bf16* qp = qkv + base + (size_t)qrow * C3 + h * D_;
#pragma unroll
    for (int c = 0; c < 4; c++) qf[c] = *(const bf16x8*)(qp + c * 16 + hi * 8);
  }

  f32x16 o[2];
#pragma unroll
  for (int d = 0; d < 2; d++)
#pragma unroll
    for (int i = 0; i < 16; i++) o[d][i] = 0.f;
  float mrun = -__builtin_inff(), lrun = 0.f;

  int nt = 2 * qb + 2;

  // prologue: stage tile 0 into buf 0
  {
    char* kb = &lds[0][0];
    char* vb = &lds[0][8192];
    gload_lds16(kptr, kb + w * 2048);
    gload_lds16(kptr + 8 * C3, kb + w * 2048 + 1024);
    gload_lds16(vptr, vb + w * 2048);
    gload_lds16(vptr + 8 * T_, vb + w * 2048 + 1024);
  }

  for (int kt = 0; kt < nt; kt++) {
    int buf = kt & 1;
    __syncthreads();  // drains my stage of buf[kt&1]; all waves done reading buf^1
    if (kt + 1 < nt) {
      char* kb = &lds[buf ^ 1][0];
      char* vb = &lds[buf ^ 1][8192];
      const __bf16* kp = kptr + (size_t)(kt + 1) * 64 * C3;
      const __bf16* vp = vptr + (kt + 1) * 64;
      gload_lds16(kp, kb + w * 2048);
      gload_lds16(kp + 8 * C3, kb + w * 2048 + 1024);
      gload_lds16(vp, vb + w * 2048);
      gload_lds16(vp + 8 * T_, vb + w * 2048 + 1024);
    }
    if (kt * 64 > q0w + 31) continue;  // wave fully below this kv tile
    char* kb = &lds[buf][0];
    char* vb = &lds[buf][8192];

    // S^T[kv][q] = K · Q^T : lane holds 32 kv values of its q row
    f32x16 s[2];
#pragma unroll
    for (int b2 = 0; b2 < 2; b2++) {
#pragma unroll
      for (int i = 0; i < 16; i++) s[b2][i] = 0.f;
#pragma unroll
      for (int c = 0; c < 4; c++) {
        bf16x8 kf = *(const bf16x8*)(kb + swz128(b2 * 32 + lq, 2 * c + hi));
        s[b2] = __builtin_amdgcn_mfma_f32_32x32x16_bf16(kf, qf[c], s[b2], 0, 0, 0);
      }
    }

    // scale into exp2 domain + causal mask (diagonal-straddling tiles only)
    bool needmask = (kt * 64 + 63) > q0w;
#pragma unroll
    for (int b2 = 0; b2 < 2; b2++)
#pragma unroll
      for (int r = 0; r < 16; r++) {
        float v = s[b2][r] * SCALE_LOG2E;
        if (needmask) {
          int kv = kt * 64 + b2 * 32 + (r & 3) + 8 * (r >> 2) + 4 * hi;
          if (kv > qrow) v = -1e30f;
        }
        s[b2][r] = v;
      }

    // row max (in-lane tree + one cross-half swap)
    float vm[16];
#pragma unroll
    for (int r = 0; r < 16; r++) vm[r] = fmaxf(s[0][r], s[1][r]);
#pragma unroll
    for (int st = 8; st >= 1; st >>= 1)
#pragma unroll
      for (int r = 0; r < st; r++) vm[r] = fmaxf(vm[r], vm[r + st]);
    float tmax = fmaxf(vm[0], __shfl_xor(vm[0], 32));

    // defer-max (T13): only rescale when some lane's max grew past threshold
    if (!__all(tmax - mrun <= 8.0f)) {
      float mnew = fmaxf(mrun, tmax);
      float al = __builtin_amdgcn_exp2f(mrun - mnew);
      mrun = mnew;
      lrun *= al;
#pragma unroll
      for (int d = 0; d < 2; d++)
#pragma unroll
        for (int i = 0; i < 16; i++) o[d][i] *= al;
    }

    // p = 2^(s - m)
#pragma unroll
    for (int b2 = 0; b2 < 2; b2++)
#pragma unroll
      for (int r = 0; r < 16; r++) s[b2][r] = __builtin_amdgcn_exp2f(s[b2][r] - mrun);

    // row sum
    float vs[16];
#pragma unroll
    for (int r = 0; r < 16; r++) vs[r] = s[0][r] + s[1][r];
#pragma unroll
    for (int st = 8; st >= 1; st >>= 1)
#pragma unroll
      for (int r = 0; r < st; r++) vs[r] += vs[r + st];
    lrun += vs[0] + __shfl_xor(vs[0], 32);

    // P^T -> B-operand fragments via cvt_pk + permlane32_swap (no LDS)
    bf16x8 pa[4];
#pragma unroll
    for (int b2 = 0; b2 < 2; b2++) {
      unsigned wg[4][2];
#pragma unroll
      for (int gg = 0; gg < 4; gg++) {
        wg[gg][0] = cvt_pk_bf16(s[b2][4 * gg + 0], s[b2][4 * gg + 1]);
        wg[gg][1] = cvt_pk_bf16(s[b2][4 * gg + 2], s[b2][4 * gg + 3]);
      }
#pragma unroll
      for (int cp = 0; cp < 2; cp++) {
        unsigned x0 = wg[2 * cp][0], x1 = wg[2 * cp][1];
        unsigned y0 = wg[2 * cp + 1][0], y1 = wg[2 * cp + 1][1];
        pl32swap(x0, y0);
        pl32swap(x1, y1);
        union { u32x4 u; bf16x8 hh; } uu;
        uu.u = (u32x4){x0, x1, y0, y1};
        pa[b2 * 2 + cp] = uu.hh;
      }
    }

    // O^T[d][q] += V^T · P^T
#pragma unroll
    for (int db = 0; db < 2; db++)
#pragma unroll
      for (int c = 0; c < 4; c++) {
        bf16x8 vf = *(const bf16x8*)(vb + swz128(db * 32 + lq, 2 * c + hi));
        o[db] = __builtin_amdgcn_mfma_f32_32x32x16_bf16(vf, pa[c], o[db], 0, 0, 0);
      }
  }

  // epilogue: lane owns q-row qrow; d = db*32 + 8*rr + 4*hi + i
  float inv = 1.f / lrun;
  __bf16* yp = y + (size_t)(b * T_ + qrow) * C_ + h * D_;
#pragma unroll
  for (int db = 0; db < 2; db++)
#pragma unroll
    for (int rr = 0; rr < 4; rr++) {
      bf16x4 ov;
#pragma unroll
      for (int i = 0; i < 4; i++) ov[i] = (__bf16)(o[db][rr * 4 + i] * inv);
      *(bf16x4*)(yp + db * 32 + rr * 8 + hi * 4) = ov;
    }
}

extern "C" void kernel_launch(void* const* d_in, const int* in_sizes, int n_in,
                              void* d_out, int out_size, void* d_ws, size_t ws_size,
                              hipStream_t stream) {
  const float* x = (const float*)d_in[0];
  const float* Wa = (const float*)d_in[1];
  const float* Wp = (const float*)d_in[2];
  float* out = (float*)d_out;
  char* ws = (char*)d_ws;

  // xb and yb share storage (xb dead after GEMM1, yb born after GEMM1)
  __bf16* xb  = (__bf16*)(ws);                 // 16 MB
  __bf16* yb  = (__bf16*)(ws);                 // 16 MB (aliases xb)
  __bf16* wat = (__bf16*)(ws + 16777216);      // 6 MB
  __bf16* wpt = (__bf16*)(ws + 23068672);      // 2 MB
  __bf16* qkv = (__bf16*)(ws + 25165824);      // 48 MB
  __bf16* vT  = (__bf16*)(ws + 75497472);      // 16 MB

  cast_x_kernel<<<8192, 256, 0, stream>>>(x, xb, (B_ * T_ * C_) / 4);
  transpose_cast_kernel<<<dim3(C3 / 32, C_ / 32), dim3(32, 8), 0, stream>>>(Wa, wat, C_, C3);
  transpose_cast_kernel<<<dim3(C_ / 32, C_ / 32), dim3(32, 8), 0, stream>>>(Wp, wpt, C_, C_);

  gemm_bt_kernel<false><<<dim3(C3 / 128, (B_ * T_) / 128), 256, 0, stream>>>(
      xb, wat, qkv, nullptr, B_ * T_, C3, C_);

  transpose_v_kernel<<<dim3(T_ / 32, C_ / 32, B_), dim3(32, 8), 0, stream>>>(qkv, vT);

  attn_kernel<<<dim3(1024), 256, 0, stream>>>(qkv, vT, yb);

  gemm_bt_kernel<true><<<dim3(C_ / 128, (B_ * T_) / 128), 256, 0, stream>>>(
      yb, wpt, nullptr, out, B_ * T_, C_, C_);
}

// Round 4
// 164.912 us; speedup vs baseline: 2.0759x; 1.0790x over previous
//
#include <hip/hip_runtime.h>
#include <hip/hip_bf16.h>

#define B_ 4
#define T_ 2048
#define C_ 1024
#define H_ 16
#define D_ 64
#define C3 3072

typedef __bf16 bf16x8 __attribute__((ext_vector_type(8)));
typedef __bf16 bf16x4 __attribute__((ext_vector_type(4)));
typedef float f32x2 __attribute__((ext_vector_type(2)));
typedef float f32x4 __attribute__((ext_vector_type(4)));
typedef float f32x16 __attribute__((ext_vector_type(16)));
typedef unsigned u32x4 __attribute__((ext_vector_type(4)));

// 0.125 (1/sqrt(D)) * log2(e): softmax computed in exp2 domain; folded into Q at GEMM1 epilogue
#define SCALE_LOG2E 0.1803368801111244f

__device__ __forceinline__ void gload_lds16(const void* g, void* lds) {
  __builtin_amdgcn_global_load_lds((const __attribute__((address_space(1))) void*)g,
                                   (__attribute__((address_space(3))) void*)lds, 16, 0, 0);
}

// byte offset into a tile with 128-byte rows (64 bf16), XOR-swizzled 16B chunks
__device__ __forceinline__ int swz128(int row, int chunk) {
  return row * 128 + ((chunk ^ (row & 7)) << 4);
}

__device__ __forceinline__ unsigned cvt_pk_bf16(float a, float b) {
  unsigned r;
  asm("v_cvt_pk_bf16_f32 %0, %1, %2" : "=v"(r) : "v"(a), "v"(b));
  return r;
}

__device__ __forceinline__ void pl32swap(unsigned& x, unsigned& y) {
  asm volatile("v_permlane32_swap_b32 %0, %1" : "+v"(x), "+v"(y));
}

__device__ __forceinline__ float fmax3(float a, float b, float c) {
  float d;
  asm("v_max3_f32 %0, %1, %2, %3" : "=v"(d) : "v"(a), "v"(b), "v"(c));
  return d;
}

__device__ __forceinline__ f32x2 pk_add(f32x2 a, f32x2 b) {
  f32x2 d;
  asm("v_pk_add_f32 %0, %1, %2" : "=v"(d) : "v"(a), "v"(b));
  return d;
}

// ---------------- cast x: fp32 -> bf16, vectorized ----------------
__global__ void cast_x_kernel(const float* __restrict__ in, __bf16* __restrict__ out, int n4) {
  int i = blockIdx.x * blockDim.x + threadIdx.x;
  if (i >= n4) return;
  float4 v = ((const float4*)in)[i];
  bf16x4 o;
  o.x = (__bf16)v.x; o.y = (__bf16)v.y; o.z = (__bf16)v.z; o.w = (__bf16)v.w;
  ((bf16x4*)out)[i] = o;
}

// ---------------- transpose + cast: fp32 [K][N] -> bf16 [N][K] ----------------
__global__ void transpose_cast_kernel(const float* __restrict__ in, __bf16* __restrict__ out,
                                      int K, int N) {
  __shared__ float tile[32][33];
  int kb = blockIdx.y * 32, nb = blockIdx.x * 32;
  int tx = threadIdx.x, ty = threadIdx.y;
#pragma unroll
  for (int i = 0; i < 4; i++) {
    int r = ty + i * 8;
    tile[r][tx] = in[(size_t)(kb + r) * N + nb + tx];
  }
  __syncthreads();
#pragma unroll
  for (int i = 0; i < 4; i++) {
    int r = ty + i * 8;
    out[(size_t)(nb + r) * K + kb + tx] = (__bf16)tile[tx][r];
  }
}

// ---------------- GEMM: C[M,N] = A[M,K] * Bt[N,K]^T  (bf16 in, f32 acc) ----------------
// MODE 0: bf16 row-major out.  MODE 1: f32 row-major out.
// MODE 2: qkv mode — Q cols (<1024) scaled by SCALE_LOG2E into Cb; K cols into Cb;
//         V cols (>=2048) written transposed into vT[(b*1024 + vcol)][t].
template <int MODE>
__global__ __launch_bounds__(256) void gemm_bt_kernel(const __bf16* __restrict__ A,
                                                      const __bf16* __restrict__ Bt,
                                                      __bf16* __restrict__ Cb,
                                                      float* __restrict__ Cf,
                                                      __bf16* __restrict__ vT,
                                                      int M, int N, int K) {
  __shared__ char ldsbuf[2 * 128 * 128];
  char* ldsA = ldsbuf;
  char* ldsB = ldsbuf + 128 * 128;
  int tid = threadIdx.x, w = tid >> 6, l = tid & 63;
  // XCD-chunked swizzle (nwg % 8 == 0 for all uses)
  int gx = gridDim.x;
  int nwg = gx * gridDim.y;
  int orig = blockIdx.y * gx + blockIdx.x;
  int cpx = nwg >> 3;
  int swz = (orig & 7) * cpx + (orig >> 3);
  int bx = swz % gx, by = swz / gx;
  int m0 = by * 128, n0 = bx * 128;
  int wr = w >> 1, wc = w & 1;
  int lr = l & 15, lhi = l >> 4;
  f32x4 acc[4][4];
#pragma unroll
  for (int m = 0; m < 4; m++)
#pragma unroll
    for (int n = 0; n < 4; n++) acc[m][n] = (f32x4){0.f, 0.f, 0.f, 0.f};

  int nK = K >> 6;
  for (int kt = 0; kt < nK; kt++) {
    int k0 = kt << 6;
    __syncthreads();
#pragma unroll
    for (int jj = 0; jj < 4; jj++) {
      int q = w * 4 + jj;
      int row = q * 8 + (l >> 3);
      int cg = (l & 7) ^ ((l >> 3) & 7);
      gload_lds16(A + (size_t)(m0 + row) * K + k0 + cg * 8, ldsA + q * 1024);
      gload_lds16(Bt + (size_t)(n0 + row) * K + k0 + cg * 8, ldsB + q * 1024);
    }
    __syncthreads();
    bf16x8 af[4][2], bfr[4][2];
#pragma unroll
    for (int m = 0; m < 4; m++) {
      int r = wr * 64 + m * 16 + lr;
#pragma unroll
      for (int kc = 0; kc < 2; kc++)
        af[m][kc] = *(const bf16x8*)(ldsA + swz128(r, kc * 4 + lhi));
    }
#pragma unroll
    for (int n = 0; n < 4; n++) {
      int r = wc * 64 + n * 16 + lr;
#pragma unroll
      for (int kc = 0; kc < 2; kc++)
        bfr[n][kc] = *(const bf16x8*)(ldsB + swz128(r, kc * 4 + lhi));
    }
#pragma unroll
    for (int kc = 0; kc < 2; kc++)
#pragma unroll
      for (int m = 0; m < 4; m++)
#pragma unroll
        for (int n = 0; n < 4; n++)
          acc[m][n] =
              __builtin_amdgcn_mfma_f32_16x16x32_bf16(af[m][kc], bfr[n][kc], acc[m][n], 0, 0, 0);
  }

  if (MODE == 2 && n0 >= 2048) {
    // V third: write transposed to vT (block rows never straddle batch: 2048 % 128 == 0)
    int bb = m0 >> 11;
    int tb = (m0 & 2047) + wr * 64 + lhi * 4;
#pragma unroll
    for (int n = 0; n < 4; n++) {
      int vcol = (n0 - 2048) + wc * 64 + n * 16 + lr;
      __bf16* vp = vT + ((size_t)bb * 1024 + vcol) * T_;
#pragma unroll
      for (int m = 0; m < 4; m++) {
        bf16x4 pv;
#pragma unroll
        for (int i = 0; i < 4; i++) pv[i] = (__bf16)acc[m][n][i];
        *(bf16x4*)(vp + tb + m * 16) = pv;
      }
    }
    return;
  }

  float oscale = (MODE == 2 && n0 < 1024) ? SCALE_LOG2E : 1.0f;
#pragma unroll
  for (int m = 0; m < 4; m++)
#pragma unroll
    for (int n = 0; n < 4; n++)
#pragma unroll
      for (int i = 0; i < 4; i++) {
        int rg = m0 + wr * 64 + m * 16 + lhi * 4 + i;
        int cg = n0 + wc * 64 + n * 16 + lr;
        if (MODE == 1)
          Cf[(size_t)rg * N + cg] = acc[m][n][i];
        else
          Cb[(size_t)rg * N + cg] = (__bf16)(acc[m][n][i] * oscale);
      }
}

// ---------------- causal flash attention, swapped-QK^T 32x32, double-buffered ----------------
// 1024 blocks; wave owns 32 q rows, lane owns 1 q row (full P row in regs).
// Q is pre-scaled by SCALE_LOG2E (folded into GEMM1 epilogue) -> scores already in log2 units.
__global__ __launch_bounds__(256) void attn_kernel(const __bf16* __restrict__ qkv,
                                                   const __bf16* __restrict__ vT,
                                                   __bf16* __restrict__ y) {
  __shared__ __align__(16) char lds[2][16384];  // [buf][ K(8KB,[kv][d]) | V^T(8KB,[d][kv]) ]
  int tid = threadIdx.x, w = tid >> 6, l = tid & 63;

  // work-balance map: 4 co-resident blocks per CU (bids mod-256 apart) sum to const work;
  // all qb of one bh share an XCD (bid&7 == bh&7) for K/V L2 reuse.
  int g = blockIdx.x >> 6, bh = blockIdx.x & 63;
  int q2 = g >> 2;
  int qb = (q2 & 1) ? ((q2 == 1) ? g + 4 : g - 12) : (15 - g);
  int b = bh >> 4, h = bh & 15;
  size_t base = (size_t)b * T_ * C3;
  int lq = l & 31, hi = l >> 5;
  int qrow = qb * 128 + w * 32 + lq;
  int q0w = qb * 128 + w * 32;

  // staging source pointers (pre-swizzled chunk)
  int lrow = l >> 3;
  int cg = (l & 7) ^ (lrow & 7);
  const __bf16* kptr = qkv + base + (size_t)(w * 16 + lrow) * C3 + C_ + h * D_ + cg * 8;
  const __bf16* vptr = vT + ((size_t)bh * D_ + w * 16 + lrow) * T_ + cg * 8;

  // Q as B-operand fragments (pre-scaled)
  bf16x8 qf[4];
  {
    const __bf16* qp = qkv + base + (size_t)qrow * C3 + h * D_;
#pragma unroll
    for (int c = 0; c < 4; c++) qf[c] = *(const bf16x8*)(qp + c * 16 + hi * 8);
  }

  f32x16 zacc;
#pragma unroll
  for (int i = 0; i < 16; i++) zacc[i] = 0.f;
  f32x16 o[2];
  o[0] = zacc; o[1] = zacc;
  float mrun = -__builtin_inff(), lrun = 0.f;

  int nt = 2 * qb + 2;

  // prologue: stage tile 0 into buf 0
  {
    char* kb = &lds[0][0];
    char* vb = &lds[0][8192];
    gload_lds16(kptr, kb + w * 2048);
    gload_lds16(kptr + 8 * C3, kb + w * 2048 + 1024);
    gload_lds16(vptr, vb + w * 2048);
    gload_lds16(vptr + 8 * T_, vb + w * 2048 + 1024);
  }

  for (int kt = 0; kt < nt; kt++) {
    int buf = kt & 1;
    __syncthreads();  // drains my stage of buf[kt&1]; all waves done reading buf^1
    if (kt + 1 < nt) {
      char* kb = &lds[buf ^ 1][0];
      char* vb = &lds[buf ^ 1][8192];
      const __bf16* kp = kptr + (size_t)(kt + 1) * 64 * C3;
      const __bf16* vp = vptr + (kt + 1) * 64;
      gload_lds16(kp, kb + w * 2048);
      gload_lds16(kp + 8 * C3, kb + w * 2048 + 1024);
      gload_lds16(vp, vb + w * 2048);
      gload_lds16(vp + 8 * T_, vb + w * 2048 + 1024);
    }
    if (kt * 64 > q0w + 31) continue;  // wave fully below this kv tile
    char* kb = &lds[buf][0];
    char* vb = &lds[buf][8192];

    // S^T[kv][q] = K · Q^T : lane holds 32 kv values of its q row (log2 units)
    f32x16 s[2];
    __builtin_amdgcn_s_setprio(1);
#pragma unroll
    for (int b2 = 0; b2 < 2; b2++) {
      bf16x8 kf0 = *(const bf16x8*)(kb + swz128(b2 * 32 + lq, hi));
      s[b2] = __builtin_amdgcn_mfma_f32_32x32x16_bf16(kf0, qf[0], zacc, 0, 0, 0);
#pragma unroll
      for (int c = 1; c < 4; c++) {
        bf16x8 kf = *(const bf16x8*)(kb + swz128(b2 * 32 + lq, 2 * c + hi));
        s[b2] = __builtin_amdgcn_mfma_f32_32x32x16_bf16(kf, qf[c], s[b2], 0, 0, 0);
      }
    }
    __builtin_amdgcn_s_setprio(0);

    // causal mask (diagonal-straddling tiles only)
    if (kt * 64 + 63 > q0w) {
#pragma unroll
      for (int b2 = 0; b2 < 2; b2++)
#pragma unroll
        for (int r = 0; r < 16; r++) {
          int kv = kt * 64 + b2 * 32 + ((r & 3) + 8 * (r >> 2)) + 4 * hi;
          if (kv > qrow) s[b2][r] = -1e30f;
        }
    }

    // row max: max3 tree (17 ops) + one cross-half swap
    {
      auto xi = [&](int i) -> float { return i < 16 ? s[0][i] : s[1][i - 16]; };
      float t10[11];
#pragma unroll
      for (int g3 = 0; g3 < 10; g3++) t10[g3] = fmax3(xi(3 * g3), xi(3 * g3 + 1), xi(3 * g3 + 2));
      t10[10] = fmaxf(xi(30), xi(31));
      float u0 = fmax3(t10[0], t10[1], t10[2]);
      float u1 = fmax3(t10[3], t10[4], t10[5]);
      float u2 = fmax3(t10[6], t10[7], t10[8]);
      float u3 = fmaxf(t10[9], t10[10]);
      float tl = fmaxf(fmax3(u0, u1, u2), u3);
      float tmax = fmaxf(tl, __shfl_xor(tl, 32));

      // defer-max (T13): only rescale when some lane's max grew past threshold
      if (!__all(tmax - mrun <= 8.0f)) {
        float mnew = fmaxf(mrun, tmax);
        float al = __builtin_amdgcn_exp2f(mrun - mnew);
        mrun = mnew;
        lrun *= al;
#pragma unroll
        for (int d = 0; d < 2; d++)
#pragma unroll
          for (int i = 0; i < 16; i++) o[d][i] *= al;
      }
    }

    // p = 2^(s - m)
#pragma unroll
    for (int b2 = 0; b2 < 2; b2++)
#pragma unroll
      for (int r = 0; r < 16; r++) s[b2][r] = __builtin_amdgcn_exp2f(s[b2][r] - mrun);

    // row sum: packed-f32 tree (15 pk_add) + one cross-half swap
    {
      f32x2 p8[8];
#pragma unroll
      for (int g3 = 0; g3 < 8; g3++) {
        f32x2 a = {s[0][2 * g3], s[0][2 * g3 + 1]};
        f32x2 b2v = {s[1][2 * g3], s[1][2 * g3 + 1]};
        p8[g3] = pk_add(a, b2v);
      }
#pragma unroll
      for (int g3 = 0; g3 < 4; g3++) p8[g3] = pk_add(p8[g3], p8[g3 + 4]);
      p8[0] = pk_add(p8[0], p8[2]);
      p8[1] = pk_add(p8[1], p8[3]);
      p8[0] = pk_add(p8[0], p8[1]);
      float rs = p8[0][0] + p8[0][1];
      lrun += rs + __shfl_xor(rs, 32);
    }

    // P^T -> B-operand fragments via cvt_pk + permlane32_swap (no LDS)
    bf16x8 pa[4];
#pragma unroll
    for (int b2 = 0; b2 < 2; b2++) {
      unsigned wg[4][2];
#pragma unroll
      for (int gg = 0; gg < 4; gg++) {
        wg[gg][0] = cvt_pk_bf16(s[b2][4 * gg + 0], s[b2][4 * gg + 1]);
        wg[gg][1] = cvt_pk_bf16(s[b2][4 * gg + 2], s[b2][4 * gg + 3]);
      }
#pragma unroll
      for (int cp = 0; cp < 2; cp++) {
        unsigned x0 = wg[2 * cp][0], x1 = wg[2 * cp][1];
        unsigned y0 = wg[2 * cp + 1][0], y1 = wg[2 * cp + 1][1];
        pl32swap(x0, y0);
        pl32swap(x1, y1);
        union { u32x4 u; bf16x8 hh; } uu;
        uu.u = (u32x4){x0, x1, y0, y1};
        pa[b2 * 2 + cp] = uu.hh;
      }
    }

    // O^T[d][q] += V^T · P^T
    __builtin_amdgcn_s_setprio(1);
#pragma unroll
    for (int db = 0; db < 2; db++)
#pragma unroll
      for (int c = 0; c < 4; c++) {
        bf16x8 vf = *(const bf16x8*)(vb + swz128(db * 32 + lq, 2 * c + hi));
        o[db] = __builtin_amdgcn_mfma_f32_32x32x16_bf16(vf, pa[c], o[db], 0, 0, 0);
      }
    __builtin_amdgcn_s_setprio(0);
  }

  // epilogue: lane owns q-row qrow; d = db*32 + 8*rr + 4*hi + i
  float inv = 1.f / lrun;
  __bf16* yp = y + (size_t)(b * T_ + qrow) * C_ + h * D_;
#pragma unroll
  for (int db = 0; db < 2; db++)
#pragma unroll
    for (int rr = 0; rr < 4; rr++) {
      bf16x4 ov;
#pragma unroll
      for (int i = 0; i < 4; i++) ov[i] = (__bf16)(o[db][rr * 4 + i] * inv);
      *(bf16x4*)(yp + db * 32 + rr * 8 + hi * 4) = ov;
    }
}

extern "C" void kernel_launch(void* const* d_in, const int* in_sizes, int n_in,
                              void* d_out, int out_size, void* d_ws, size_t ws_size,
                              hipStream_t stream) {
  const float* x = (const float*)d_in[0];
  const float* Wa = (const float*)d_in[1];
  const float* Wp = (const float*)d_in[2];
  float* out = (float*)d_out;
  char* ws = (char*)d_ws;

  // xb and yb share storage (xb dead after GEMM1, yb born after GEMM1)
  __bf16* xb  = (__bf16*)(ws);                 // 16 MB
  __bf16* yb  = (__bf16*)(ws);                 // 16 MB (aliases xb)
  __bf16* wat = (__bf16*)(ws + 16777216);      // 6 MB
  __bf16* wpt = (__bf16*)(ws + 23068672);      // 2 MB
  __bf16* qkv = (__bf16*)(ws + 25165824);      // 48 MB (V third unused)
  __bf16* vT  = (__bf16*)(ws + 75497472);      // 16 MB

  cast_x_kernel<<<8192, 256, 0, stream>>>(x, xb, (B_ * T_ * C_) / 4);
  transpose_cast_kernel<<<dim3(C3 / 32, C_ / 32), dim3(32, 8), 0, stream>>>(Wa, wat, C_, C3);
  transpose_cast_kernel<<<dim3(C_ / 32, C_ / 32), dim3(32, 8), 0, stream>>>(Wp, wpt, C_, C_);

  // qkv = x @ W_attn; Q cols pre-scaled, V cols written transposed to vT
  gemm_bt_kernel<2><<<dim3(C3 / 128, (B_ * T_) / 128), 256, 0, stream>>>(
      xb, wat, qkv, nullptr, vT, B_ * T_, C3, C_);

  attn_kernel<<<dim3(1024), 256, 0, stream>>>(qkv, vT, yb);

  gemm_bt_kernel<1><<<dim3(C_ / 128, (B_ * T_) / 128), 256, 0, stream>>>(
      yb, wpt, nullptr, out, nullptr, B_ * T_, C_, C_);
}

// Round 5
// 155.680 us; speedup vs baseline: 2.1990x; 1.0593x over previous
//
#include <hip/hip_runtime.h>
#include <hip/hip_bf16.h>

#define B_ 4
#define T_ 2048
#define C_ 1024
#define H_ 16
#define D_ 64
#define C3 3072

typedef __bf16 bf16x8 __attribute__((ext_vector_type(8)));
typedef __bf16 bf16x4 __attribute__((ext_vector_type(4)));
typedef float f32x2 __attribute__((ext_vector_type(2)));
typedef float f32x4 __attribute__((ext_vector_type(4)));
typedef float f32x16 __attribute__((ext_vector_type(16)));
typedef unsigned u32x4 __attribute__((ext_vector_type(4)));

// 0.125 (1/sqrt(D)) * log2(e): softmax computed in exp2 domain; folded into Q at GEMM1 epilogue
#define SCALE_LOG2E 0.1803368801111244f

__device__ __forceinline__ void gload_lds16(const void* g, void* lds) {
  __builtin_amdgcn_global_load_lds((const __attribute__((address_space(1))) void*)g,
                                   (__attribute__((address_space(3))) void*)lds, 16, 0, 0);
}

// byte offset into a tile with 128-byte rows (64 bf16), XOR-swizzled 16B chunks
__device__ __forceinline__ int swz128(int row, int chunk) {
  return row * 128 + ((chunk ^ (row & 7)) << 4);
}

__device__ __forceinline__ unsigned cvt_pk_bf16(float a, float b) {
  unsigned r;
  asm("v_cvt_pk_bf16_f32 %0, %1, %2" : "=v"(r) : "v"(a), "v"(b));
  return r;
}

__device__ __forceinline__ void pl32swap(unsigned& x, unsigned& y) {
  asm volatile("v_permlane32_swap_b32 %0, %1" : "+v"(x), "+v"(y));
}

__device__ __forceinline__ float fmax3(float a, float b, float c) {
  float d;
  asm("v_max3_f32 %0, %1, %2, %3" : "=v"(d) : "v"(a), "v"(b), "v"(c));
  return d;
}

__device__ __forceinline__ f32x2 pk_add(f32x2 a, f32x2 b) {
  f32x2 d;
  asm("v_pk_add_f32 %0, %1, %2" : "=v"(d) : "v"(a), "v"(b));
  return d;
}

// ---------------- cast x: fp32 -> bf16, vectorized ----------------
__global__ void cast_x_kernel(const float* __restrict__ in, __bf16* __restrict__ out, int n4) {
  int i = blockIdx.x * blockDim.x + threadIdx.x;
  if (i >= n4) return;
  float4 v = ((const float4*)in)[i];
  bf16x4 o;
  o.x = (__bf16)v.x; o.y = (__bf16)v.y; o.z = (__bf16)v.z; o.w = (__bf16)v.w;
  ((bf16x4*)out)[i] = o;
}

// ---------------- transpose + cast: fp32 [K][N] -> bf16 [N][K] ----------------
__global__ void transpose_cast_kernel(const float* __restrict__ in, __bf16* __restrict__ out,
                                      int K, int N) {
  __shared__ float tile[32][33];
  int kb = blockIdx.y * 32, nb = blockIdx.x * 32;
  int tx = threadIdx.x, ty = threadIdx.y;
#pragma unroll
  for (int i = 0; i < 4; i++) {
    int r = ty + i * 8;
    tile[r][tx] = in[(size_t)(kb + r) * N + nb + tx];
  }
  __syncthreads();
#pragma unroll
  for (int i = 0; i < 4; i++) {
    int r = ty + i * 8;
    out[(size_t)(nb + r) * K + kb + tx] = (__bf16)tile[tx][r];
  }
}

// ---------------- GEMM: C[M,N] = A[M,K] * Bt[N,K]^T  (bf16 in, f32 acc) ----------------
// Double-buffered LDS, one barrier per K-step (stage t+1 after barrier, drained next iter).
// MODE 0: bf16 row-major out.  MODE 1: f32 row-major out.
// MODE 2: qkv mode — Q cols (<1024) scaled by SCALE_LOG2E into Cb; K cols into Cb;
//         V cols (>=2048) written transposed into vT[(b*1024 + vcol)][t].
template <int MODE>
__global__ __launch_bounds__(256) void gemm_bt_kernel(const __bf16* __restrict__ A,
                                                      const __bf16* __restrict__ Bt,
                                                      __bf16* __restrict__ Cb,
                                                      float* __restrict__ Cf,
                                                      __bf16* __restrict__ vT,
                                                      int M, int N, int K) {
  __shared__ __align__(16) char lds[2][32768];  // [buf][ A 16KB | B 16KB ]
  int tid = threadIdx.x, w = tid >> 6, l = tid & 63;
  // XCD-chunked swizzle (nwg % 8 == 0 for all uses)
  int gx = gridDim.x;
  int nwg = gx * gridDim.y;
  int orig = blockIdx.y * gx + blockIdx.x;
  int cpx = nwg >> 3;
  int swz = (orig & 7) * cpx + (orig >> 3);
  int bx = swz % gx, by = swz / gx;
  int m0 = by * 128, n0 = bx * 128;
  int wr = w >> 1, wc = w & 1;
  int lr = l & 15, lhi = l >> 4;

  int srow = l >> 3;              // staging: row within 8-row quad
  int cg = (l & 7) ^ (srow & 7);  // pre-swizzled global chunk

  f32x4 acc[4][4];
#pragma unroll
  for (int m = 0; m < 4; m++)
#pragma unroll
    for (int n = 0; n < 4; n++) acc[m][n] = (f32x4){0.f, 0.f, 0.f, 0.f};

  auto stage = [&](int kt, int buf) {
    int k0 = kt << 6;
    char* la = &lds[buf][0];
    char* lb = &lds[buf][16384];
#pragma unroll
    for (int jj = 0; jj < 4; jj++) {
      int q = w * 4 + jj;
      int row = q * 8 + srow;
      gload_lds16(A + (size_t)(m0 + row) * K + k0 + cg * 8, la + q * 1024);
      gload_lds16(Bt + (size_t)(n0 + row) * K + k0 + cg * 8, lb + q * 1024);
    }
  };

  int nK = K >> 6;
  stage(0, 0);  // prologue

  for (int kt = 0; kt < nK; kt++) {
    int buf = kt & 1;
    __syncthreads();  // drains my tile-kt loads (issued last iter); all waves done reading buf^1
    if (kt + 1 < nK) stage(kt + 1, buf ^ 1);
    char* la = &lds[buf][0];
    char* lb = &lds[buf][16384];

    bf16x8 af[4][2], bfr[4][2];
#pragma unroll
    for (int m = 0; m < 4; m++) {
      int r = wr * 64 + m * 16 + lr;
#pragma unroll
      for (int kc = 0; kc < 2; kc++)
        af[m][kc] = *(const bf16x8*)(la + swz128(r, kc * 4 + lhi));
    }
#pragma unroll
    for (int n = 0; n < 4; n++) {
      int r = wc * 64 + n * 16 + lr;
#pragma unroll
      for (int kc = 0; kc < 2; kc++)
        bfr[n][kc] = *(const bf16x8*)(lb + swz128(r, kc * 4 + lhi));
    }
#pragma unroll
    for (int kc = 0; kc < 2; kc++)
#pragma unroll
      for (int m = 0; m < 4; m++)
#pragma unroll
        for (int n = 0; n < 4; n++)
          acc[m][n] =
              __builtin_amdgcn_mfma_f32_16x16x32_bf16(af[m][kc], bfr[n][kc], acc[m][n], 0, 0, 0);
  }

  if (MODE == 2 && n0 >= 2048) {
    // V third: write transposed to vT (block rows never straddle batch: 2048 % 128 == 0)
    int bb = m0 >> 11;
    int tb = (m0 & 2047) + wr * 64 + lhi * 4;
#pragma unroll
    for (int n = 0; n < 4; n++) {
      int vcol = (n0 - 2048) + wc * 64 + n * 16 + lr;
      __bf16* vp = vT + ((size_t)bb * 1024 + vcol) * T_;
#pragma unroll
      for (int m = 0; m < 4; m++) {
        bf16x4 pv;
#pragma unroll
        for (int i = 0; i < 4; i++) pv[i] = (__bf16)acc[m][n][i];
        *(bf16x4*)(vp + tb + m * 16) = pv;
      }
    }
    return;
  }

  float oscale = (MODE == 2 && n0 < 1024) ? SCALE_LOG2E : 1.0f;
#pragma unroll
  for (int m = 0; m < 4; m++)
#pragma unroll
    for (int n = 0; n < 4; n++)
#pragma unroll
      for (int i = 0; i < 4; i++) {
        int rg = m0 + wr * 64 + m * 16 + lhi * 4 + i;
        int cg2 = n0 + wc * 64 + n * 16 + lr;
        if (MODE == 1)
          Cf[(size_t)rg * N + cg2] = acc[m][n][i];
        else
          Cb[(size_t)rg * N + cg2] = (__bf16)(acc[m][n][i] * oscale);
      }
}

// ---------------- causal flash attention, swapped-QK^T 32x32, double-buffered ----------------
// 1024 blocks; wave owns 32 q rows, lane owns 1 q row (full P row in regs).
// Q is pre-scaled by SCALE_LOG2E (folded into GEMM1 epilogue) -> scores already in log2 units.
__global__ __launch_bounds__(256) void attn_kernel(const __bf16* __restrict__ qkv,
                                                   const __bf16* __restrict__ vT,
                                                   __bf16* __restrict__ y) {
  __shared__ __align__(16) char lds[2][16384];  // [buf][ K(8KB,[kv][d]) | V^T(8KB,[d][kv]) ]
  int tid = threadIdx.x, w = tid >> 6, l = tid & 63;

  // work-balance map: 4 co-resident blocks per CU (bids mod-256 apart) sum to const work;
  // all qb of one bh share an XCD (bid&7 == bh&7) for K/V L2 reuse.
  int g = blockIdx.x >> 6, bh = blockIdx.x & 63;
  int q2 = g >> 2;
  int qb = (q2 & 1) ? ((q2 == 1) ? g + 4 : g - 12) : (15 - g);
  int b = bh >> 4, h = bh & 15;
  size_t base = (size_t)b * T_ * C3;
  int lq = l & 31, hi = l >> 5;
  int qrow = qb * 128 + w * 32 + lq;
  int q0w = qb * 128 + w * 32;

  // staging source pointers (pre-swizzled chunk)
  int lrow = l >> 3;
  int cg = (l & 7) ^ (lrow & 7);
  const __bf16* kptr = qkv + base + (size_t)(w * 16 + lrow) * C3 + C_ + h * D_ + cg * 8;
  const __bf16* vptr = vT + ((size_t)bh * D_ + w * 16 + lrow) * T_ + cg * 8;

  // Q as B-operand fragments (pre-scaled)
  bf16x8 qf[4];
  {
    const __bf16* qp = qkv + base + (size_t)qrow * C3 + h * D_;
#pragma unroll
    for (int c = 0; c < 4; c++) qf[c] = *(const bf16x8*)(qp + c * 16 + hi * 8);
  }

  f32x16 zacc;
#pragma unroll
  for (int i = 0; i < 16; i++) zacc[i] = 0.f;
  f32x16 o[2];
  o[0] = zacc; o[1] = zacc;
  float mrun = -__builtin_inff(), lrun = 0.f;

  int nt = 2 * qb + 2;

  // prologue: stage tile 0 into buf 0
  {
    char* kb = &lds[0][0];
    char* vb = &lds[0][8192];
    gload_lds16(kptr, kb + w * 2048);
    gload_lds16(kptr + 8 * C3, kb + w * 2048 + 1024);
    gload_lds16(vptr, vb + w * 2048);
    gload_lds16(vptr + 8 * T_, vb + w * 2048 + 1024);
  }

  for (int kt = 0; kt < nt; kt++) {
    int buf = kt & 1;
    __syncthreads();  // drains my stage of buf[kt&1]; all waves done reading buf^1
    if (kt + 1 < nt) {
      char* kb = &lds[buf ^ 1][0];
      char* vb = &lds[buf ^ 1][8192];
      const __bf16* kp = kptr + (size_t)(kt + 1) * 64 * C3;
      const __bf16* vp = vptr + (kt + 1) * 64;
      gload_lds16(kp, kb + w * 2048);
      gload_lds16(kp + 8 * C3, kb + w * 2048 + 1024);
      gload_lds16(vp, vb + w * 2048);
      gload_lds16(vp + 8 * T_, vb + w * 2048 + 1024);
    }
    if (kt * 64 > q0w + 31) continue;  // wave fully below this kv tile
    char* kb = &lds[buf][0];
    char* vb = &lds[buf][8192];

    // S^T[kv][q] = K · Q^T : lane holds 32 kv values of its q row (log2 units)
    f32x16 s[2];
    __builtin_amdgcn_s_setprio(1);
#pragma unroll
    for (int b2 = 0; b2 < 2; b2++) {
      bf16x8 kf0 = *(const bf16x8*)(kb + swz128(b2 * 32 + lq, hi));
      s[b2] = __builtin_amdgcn_mfma_f32_32x32x16_bf16(kf0, qf[0], zacc, 0, 0, 0);
#pragma unroll
      for (int c = 1; c < 4; c++) {
        bf16x8 kf = *(const bf16x8*)(kb + swz128(b2 * 32 + lq, 2 * c + hi));
        s[b2] = __builtin_amdgcn_mfma_f32_32x32x16_bf16(kf, qf[c], s[b2], 0, 0, 0);
      }
    }
    __builtin_amdgcn_s_setprio(0);

    // causal mask (diagonal-straddling tiles only)
    if (kt * 64 + 63 > q0w) {
#pragma unroll
      for (int b2 = 0; b2 < 2; b2++)
#pragma unroll
        for (int r = 0; r < 16; r++) {
          int kv = kt * 64 + b2 * 32 + ((r & 3) + 8 * (r >> 2)) + 4 * hi;
          if (kv > qrow) s[b2][r] = -1e30f;
        }
    }

    // row max: max3 tree (17 ops) + one cross-half swap
    {
      auto xi = [&](int i) -> float { return i < 16 ? s[0][i] : s[1][i - 16]; };
      float t10[11];
#pragma unroll
      for (int g3 = 0; g3 < 10; g3++) t10[g3] = fmax3(xi(3 * g3), xi(3 * g3 + 1), xi(3 * g3 + 2));
      t10[10] = fmaxf(xi(30), xi(31));
      float u0 = fmax3(t10[0], t10[1], t10[2]);
      float u1 = fmax3(t10[3], t10[4], t10[5]);
      float u2 = fmax3(t10[6], t10[7], t10[8]);
      float u3 = fmaxf(t10[9], t10[10]);
      float tl = fmaxf(fmax3(u0, u1, u2), u3);
      float tmax = fmaxf(tl, __shfl_xor(tl, 32));

      // defer-max (T13): only rescale when some lane's max grew past threshold
      if (!__all(tmax - mrun <= 8.0f)) {
        float mnew = fmaxf(mrun, tmax);
        float al = __builtin_amdgcn_exp2f(mrun - mnew);
        mrun = mnew;
        lrun *= al;
#pragma unroll
        for (int d = 0; d < 2; d++)
#pragma unroll
          for (int i = 0; i < 16; i++) o[d][i] *= al;
      }
    }

    // p = 2^(s - m)
#pragma unroll
    for (int b2 = 0; b2 < 2; b2++)
#pragma unroll
      for (int r = 0; r < 16; r++) s[b2][r] = __builtin_amdgcn_exp2f(s[b2][r] - mrun);

    // row sum: packed-f32 tree (15 pk_add) + one cross-half swap
    {
      f32x2 p8[8];
#pragma unroll
      for (int g3 = 0; g3 < 8; g3++) {
        f32x2 a = {s[0][2 * g3], s[0][2 * g3 + 1]};
        f32x2 b2v = {s[1][2 * g3], s[1][2 * g3 + 1]};
        p8[g3] = pk_add(a, b2v);
      }
#pragma unroll
      for (int g3 = 0; g3 < 4; g3++) p8[g3] = pk_add(p8[g3], p8[g3 + 4]);
      p8[0] = pk_add(p8[0], p8[2]);
      p8[1] = pk_add(p8[1], p8[3]);
      p8[0] = pk_add(p8[0], p8[1]);
      float rs = p8[0][0] + p8[0][1];
      lrun += rs + __shfl_xor(rs, 32);
    }

    // P^T -> B-operand fragments via cvt_pk + permlane32_swap (no LDS)
    bf16x8 pa[4];
#pragma unroll
    for (int b2 = 0; b2 < 2; b2++) {
      unsigned wg[4][2];
#pragma unroll
      for (int gg = 0; gg < 4; gg++) {
        wg[gg][0] = cvt_pk_bf16(s[b2][4 * gg + 0], s[b2][4 * gg + 1]);
        wg[gg][1] = cvt_pk_bf16(s[b2][4 * gg + 2], s[b2][4 * gg + 3]);
      }
#pragma unroll
      for (int cp = 0; cp < 2; cp++) {
        unsigned x0 = wg[2 * cp][0], x1 = wg[2 * cp][1];
        unsigned y0 = wg[2 * cp + 1][0], y1 = wg[2 * cp + 1][1];
        pl32swap(x0, y0);
        pl32swap(x1, y1);
        union { u32x4 u; bf16x8 hh; } uu;
        uu.u = (u32x4){x0, x1, y0, y1};
        pa[b2 * 2 + cp] = uu.hh;
      }
    }

    // O^T[d][q] += V^T · P^T
    __builtin_amdgcn_s_setprio(1);
#pragma unroll
    for (int db = 0; db < 2; db++)
#pragma unroll
      for (int c = 0; c < 4; c++) {
        bf16x8 vf = *(const bf16x8*)(vb + swz128(db * 32 + lq, 2 * c + hi));
        o[db] = __builtin_amdgcn_mfma_f32_32x32x16_bf16(vf, pa[c], o[db], 0, 0, 0);
      }
    __builtin_amdgcn_s_setprio(0);
  }

  // epilogue: lane owns q-row qrow; d = db*32 + 8*rr + 4*hi + i
  float inv = 1.f / lrun;
  __bf16* yp = y + (size_t)(b * T_ + qrow) * C_ + h * D_;
#pragma unroll
  for (int db = 0; db < 2; db++)
#pragma unroll
    for (int rr = 0; rr < 4; rr++) {
      bf16x4 ov;
#pragma unroll
      for (int i = 0; i < 4; i++) ov[i] = (__bf16)(o[db][rr * 4 + i] * inv);
      *(bf16x4*)(yp + db * 32 + rr * 8 + hi * 4) = ov;
    }
}

extern "C" void kernel_launch(void* const* d_in, const int* in_sizes, int n_in,
                              void* d_out, int out_size, void* d_ws, size_t ws_size,
                              hipStream_t stream) {
  const float* x = (const float*)d_in[0];
  const float* Wa = (const float*)d_in[1];
  const float* Wp = (const float*)d_in[2];
  float* out = (float*)d_out;
  char* ws = (char*)d_ws;

  // xb and yb share storage (xb dead after GEMM1, yb born after GEMM1)
  __bf16* xb  = (__bf16*)(ws);                 // 16 MB
  __bf16* yb  = (__bf16*)(ws);                 // 16 MB (aliases xb)
  __bf16* wat = (__bf16*)(ws + 16777216);      // 6 MB
  __bf16* wpt = (__bf16*)(ws + 23068672);      // 2 MB
  __bf16* qkv = (__bf16*)(ws + 25165824);      // 48 MB (V third unused)
  __bf16* vT  = (__bf16*)(ws + 75497472);      // 16 MB

  cast_x_kernel<<<8192, 256, 0, stream>>>(x, xb, (B_ * T_ * C_) / 4);
  transpose_cast_kernel<<<dim3(C3 / 32, C_ / 32), dim3(32, 8), 0, stream>>>(Wa, wat, C_, C3);
  transpose_cast_kernel<<<dim3(C_ / 32, C_ / 32), dim3(32, 8), 0, stream>>>(Wp, wpt, C_, C_);

  // qkv = x @ W_attn; Q cols pre-scaled, V cols written transposed to vT
  gemm_bt_kernel<2><<<dim3(C3 / 128, (B_ * T_) / 128), 256, 0, stream>>>(
      xb, wat, qkv, nullptr, vT, B_ * T_, C3, C_);

  attn_kernel<<<dim3(1024), 256, 0, stream>>>(qkv, vT, yb);

  gemm_bt_kernel<1><<<dim3(C_ / 128, (B_ * T_) / 128), 256, 0, stream>>>(
      yb, wpt, nullptr, out, nullptr, B_ * T_, C_, C_);
}